// Round 6
// baseline (112.088 us; speedup 1.0000x reference)
//
#include <hip/hip_runtime.h>
#include <math.h>

#define B 8
#define C 512
#define L 8192
#define CS 16
#define N 512      // L/CS chunk steps
#define C8 64      // C/8 bottleneck dim
#define SEG 16     // EMA scan segments per row
#define SL 32      // N/SEG steps per segment
#define ROWS 4096  // B*N total chunk rows

typedef float floatx4 __attribute__((ext_vector_type(4)));

// ---------------------------------------------------------------------------
// Kernel 1: chunked average pooling.  x [B,C,L] -> pool [B,N,C]
// Block = one (b, 16c, 16n) tile. Reads: each wave streams 1 KB contiguous.
// LDS-transpose so writes are 64 B-contiguous in c. Reads populate L3 with x.
// ---------------------------------------------------------------------------
__global__ __launch_bounds__(256) void pool_k(const float* __restrict__ x,
                                              float* __restrict__ pool) {
    __shared__ float tile[16][17];          // +1 pad: conflict-free transpose
    const int t = threadIdx.x;
    const int bid = blockIdx.x;             // B * 32 * 32 = 8192
    const int nt = bid & 31;
    const int ct = (bid >> 5) & 31;
    const int b  = bid >> 10;
    const int w    = t >> 6;                // wave 0..3
    const int lane = t & 63;

#pragma unroll
    for (int i = 0; i < 4; ++i) {
        const int c_local = i * 4 + w;
        const int c = ct * 16 + c_local;
        const float4 v = reinterpret_cast<const float4*>(x)[
            (size_t)(b * C + c) * (L / 4) + nt * 64 + lane];
        float s = v.x + v.y + v.z + v.w;
        s += __shfl_down(s, 1, 4);
        s += __shfl_down(s, 2, 4);
        if ((lane & 3) == 0)
            tile[c_local][lane >> 2] = s * (1.0f / 16.0f);
    }
    __syncthreads();

    const int n_local = t >> 4;
    const int c_local = t & 15;
    pool[(size_t)(b * N + nt * 16 + n_local) * C + ct * 16 + c_local] =
        tile[c_local][n_local];
}

// ---------------------------------------------------------------------------
// Kernel 2: EMA carries only (segment-local scan endpoint per (b,s,c)).
// pool is NOT modified. Also folds in the tiny weight re-pack.
// ---------------------------------------------------------------------------
__global__ __launch_bounds__(256) void emaA_k(const float* __restrict__ gamma,
                                              const float* __restrict__ pool,
                                              float* __restrict__ carry,
                                              const float* __restrict__ w1,
                                              const float* __restrict__ w2,
                                              float* __restrict__ w1t4,
                                              float* __restrict__ w2t4) {
    const int id = blockIdx.x * 256 + threadIdx.x;      // B*SEG*C = 65536
    if (id < C8 * C) {
        {   // w1 [C8][C] -> float4-interleaved [(k/4)*C8 + o][4]
            const int o = id >> 9;
            const int k = id & (C - 1);
            w1t4[((k >> 2) * C8 + o) * 4 + (k & 3)] = w1[id];
        }
        {   // w2 [C][C8] -> float4-interleaved [(k/4)*C + c][4]
            const int c = id >> 6;
            const int k = id & (C8 - 1);
            w2t4[((k >> 2) * C + c) * 4 + (k & 3)] = w2[id];
        }
    }
    const int c = id & (C - 1);
    const int rest = id >> 9;
    const int s = rest & (SEG - 1);
    const int b = rest >> 4;
    const float g = gamma[c];
    const float omg = 1.0f - g;
    const float* p = pool + ((size_t)(b * N + s * SL)) * C + c;
    float y = 0.0f;
#pragma unroll 8
    for (int i = 0; i < SL; ++i)
        y = fmaf(g, y, omg * p[(size_t)i * C]);
    carry[(size_t)(b * SEG + s) * C + c] = y;
}

// ---------------------------------------------------------------------------
// Kernel 3: SE GEMM1 with fused EMA finish.
// Block (rb, ks): rows rb*32..+31 = segment (b = rb/16, s = rb%16).
// Stage raw pool half-k, seed scan with E_{s-1} from carries (EMA linearity),
// scan 32 rows in LDS, then register-tiled GEMM -> ph[ks][ROWS][C8].
// ---------------------------------------------------------------------------
__global__ __launch_bounds__(256) void se1_k(const float* __restrict__ pool,
                                             const float* __restrict__ carry,
                                             const float* __restrict__ gamma,
                                             const float* __restrict__ w1t4,
                                             float* __restrict__ ph) {
    __shared__ float e_s[32 * 256];   // 32KB: [row_local][k_half]
    const int t = threadIdx.x;
    const int rb = blockIdx.x >> 1;
    const int ks = blockIdx.x & 1;
    const int b = rb >> 4;
    const int s = rb & 15;
    const int row0 = rb * 32;

    // stage 32 rows x 256 k (2048 float4, 8/thread), coalesced
#pragma unroll
    for (int i = 0; i < 8; ++i) {
        const int idx = i * 256 + t;        // 0..2047
        const int r = idx >> 6;             // 64 float4 per row-half
        const int kk = idx & 63;
        reinterpret_cast<float4*>(e_s)[idx] =
            reinterpret_cast<const float4*>(pool + (size_t)(row0 + r) * C + ks * 256)[kk];
    }
    __syncthreads();

    // EMA finish: thread t = local channel; c = ks*256 + t.
    {
        const int c = ks * 256 + t;
        const float g = gamma[c];
        const float omg = 1.0f - g;
        float g32 = g * g;
        g32 *= g32; g32 *= g32; g32 *= g32; g32 *= g32;   // g^32
        float E = 0.0f;
        const float* cb = carry + (size_t)b * SEG * C + c;
        for (int tt = 0; tt < s; ++tt)
            E = fmaf(g32, E, cb[(size_t)tt * C]);
        float y = E;                       // state entering this segment
#pragma unroll
        for (int r = 0; r < 32; ++r) {
            y = fmaf(g, y, omg * e_s[r * 256 + t]);
            e_s[r * 256 + t] = y;
        }
    }
    __syncthreads();

    const int oc = t & 31;
    const int jg = t >> 5;                  // rows jg*4..+3
    float a0[4] = {0.f, 0.f, 0.f, 0.f};
    float a1[4] = {0.f, 0.f, 0.f, 0.f};
    const float4* w1v = reinterpret_cast<const float4*>(w1t4);
    const float4* es4 = reinterpret_cast<const float4*>(e_s);
#pragma unroll 4
    for (int k4 = 0; k4 < 64; ++k4) {
        const float4 wa = w1v[(size_t)(ks * 64 + k4) * C8 + oc];
        const float4 wb = w1v[(size_t)(ks * 64 + k4) * C8 + oc + 32];
#pragma unroll
        for (int r = 0; r < 4; ++r) {
            const float4 ev = es4[(jg * 4 + r) * 64 + k4];
            a0[r] = fmaf(wa.x, ev.x, a0[r]); a0[r] = fmaf(wa.y, ev.y, a0[r]);
            a0[r] = fmaf(wa.z, ev.z, a0[r]); a0[r] = fmaf(wa.w, ev.w, a0[r]);
            a1[r] = fmaf(wb.x, ev.x, a1[r]); a1[r] = fmaf(wb.y, ev.y, a1[r]);
            a1[r] = fmaf(wb.z, ev.z, a1[r]); a1[r] = fmaf(wb.w, ev.w, a1[r]);
        }
    }
    float* pbase = ph + ((size_t)ks * ROWS + row0) * C8;
#pragma unroll
    for (int r = 0; r < 4; ++r) {
        pbase[(size_t)(jg * 4 + r) * C8 + oc]      = a0[r];
        pbase[(size_t)(jg * 4 + r) * C8 + oc + 32] = a1[r];
    }
}

// ---------------------------------------------------------------------------
// Kernel 4: SE GEMM2.  h = relu(b1 + ph0 + ph1); gate = sigmoid(h w2^T + b2)
// Output layout [B,C,N]: two float4 register stores per thread column.
// ---------------------------------------------------------------------------
__global__ __launch_bounds__(256) void se2_k(const float* __restrict__ ph,
                                             const float* __restrict__ b1,
                                             const float* __restrict__ w2t4,
                                             const float* __restrict__ b2,
                                             float* __restrict__ gate) {
    __shared__ float h_s[32 * C8];   // 8KB [row_local][o]
    const int t = threadIdx.x;
    const int rb = blockIdx.x >> 2;
    const int ct = blockIdx.x & 3;
    const int row0 = rb * 32;
    const int b = rb >> 4;
    const int n0 = (rb & 15) * 32;

    // stage h = relu(b1 + ph0 + ph1): 512 float4, 2/thread
    {
        const float4* p0 = reinterpret_cast<const float4*>(ph + (size_t)row0 * C8);
        const float4* p1 = reinterpret_cast<const float4*>(ph + (size_t)(ROWS + row0) * C8);
        const float4* b1v = reinterpret_cast<const float4*>(b1);
#pragma unroll
        for (int i = 0; i < 2; ++i) {
            const int idx = i * 256 + t;
            const float4 u = p0[idx];
            const float4 v = p1[idx];
            const float4 bb = b1v[idx & 15];
            float4 hv;
            hv.x = fmaxf(bb.x + u.x + v.x, 0.f);
            hv.y = fmaxf(bb.y + u.y + v.y, 0.f);
            hv.z = fmaxf(bb.z + u.z + v.z, 0.f);
            hv.w = fmaxf(bb.w + u.w + v.w, 0.f);
            reinterpret_cast<float4*>(h_s)[idx] = hv;
        }
    }
    __syncthreads();

    const int cl = t & 63;
    const int jg = t >> 6;                  // rows (n) jg*8..+7
    const int c = ct * 128 + cl;
    float acc0[8], acc1[8];
    const float bb0 = b2[c];
    const float bb1 = b2[c + 64];
#pragma unroll
    for (int j = 0; j < 8; ++j) { acc0[j] = bb0; acc1[j] = bb1; }
    const float4* w2v = reinterpret_cast<const float4*>(w2t4);
    const float4* hs4 = reinterpret_cast<const float4*>(h_s);
#pragma unroll
    for (int k4 = 0; k4 < 16; ++k4) {
        const float4 wa = w2v[(size_t)k4 * C + c];
        const float4 wb = w2v[(size_t)k4 * C + c + 64];
#pragma unroll
        for (int j = 0; j < 8; ++j) {
            const float4 hv = hs4[(jg * 8 + j) * 16 + k4];
            acc0[j] = fmaf(wa.x, hv.x, acc0[j]); acc0[j] = fmaf(wa.y, hv.y, acc0[j]);
            acc0[j] = fmaf(wa.z, hv.z, acc0[j]); acc0[j] = fmaf(wa.w, hv.w, acc0[j]);
            acc1[j] = fmaf(wb.x, hv.x, acc1[j]); acc1[j] = fmaf(wb.y, hv.y, acc1[j]);
            acc1[j] = fmaf(wb.z, hv.z, acc1[j]); acc1[j] = fmaf(wb.w, hv.w, acc1[j]);
        }
    }
    // gate [B,C,N]: 8 consecutive n per column per thread
    {
        float4 o0, o1;
        float* g0 = gate + ((size_t)(b * C + c)) * N + n0 + jg * 8;
        float* g1 = gate + ((size_t)(b * C + c + 64)) * N + n0 + jg * 8;
        o0.x = 1.0f / (1.0f + __expf(-acc0[0]));
        o0.y = 1.0f / (1.0f + __expf(-acc0[1]));
        o0.z = 1.0f / (1.0f + __expf(-acc0[2]));
        o0.w = 1.0f / (1.0f + __expf(-acc0[3]));
        o1.x = 1.0f / (1.0f + __expf(-acc0[4]));
        o1.y = 1.0f / (1.0f + __expf(-acc0[5]));
        o1.z = 1.0f / (1.0f + __expf(-acc0[6]));
        o1.w = 1.0f / (1.0f + __expf(-acc0[7]));
        reinterpret_cast<float4*>(g0)[0] = o0;
        reinterpret_cast<float4*>(g0)[1] = o1;
        o0.x = 1.0f / (1.0f + __expf(-acc1[0]));
        o0.y = 1.0f / (1.0f + __expf(-acc1[1]));
        o0.z = 1.0f / (1.0f + __expf(-acc1[2]));
        o0.w = 1.0f / (1.0f + __expf(-acc1[3]));
        o1.x = 1.0f / (1.0f + __expf(-acc1[4]));
        o1.y = 1.0f / (1.0f + __expf(-acc1[5]));
        o1.z = 1.0f / (1.0f + __expf(-acc1[6]));
        o1.w = 1.0f / (1.0f + __expf(-acc1[7]));
        reinterpret_cast<float4*>(g1)[0] = o0;
        reinterpret_cast<float4*>(g1)[1] = o1;
    }
}

// ---------------------------------------------------------------------------
// Kernel 5: apply gate.  out[b,c,l] = gate[b,c,l/16] * x[b,c,l]
// x read should hit L3 (pool warmed it). out written NON-TEMPORALLY (native
// ext_vector_type for the builtin) so the write stream does not evict x.
// ---------------------------------------------------------------------------
__global__ __launch_bounds__(256) void apply_k(const float* __restrict__ x,
                                               const float* __restrict__ gate,
                                               float* __restrict__ out) {
    const size_t p = (size_t)blockIdx.x * 256 + threadIdx.x;    // pair index
    const int pairs_per_row = L / 8;             // 1024 pairs per (b,c) row
    const int bc = (int)(p / pairs_per_row);
    const int wi = (int)(p % pairs_per_row);
    const int n = wi >> 1;                       // 2 pairs per 16-elem chunk

    const float g = gate[(size_t)bc * N + n];
    const floatx4* xv = reinterpret_cast<const floatx4*>(x) + p * 2;
    floatx4 v0 = xv[0];
    floatx4 v1 = xv[1];
    v0 *= g;
    v1 *= g;
    floatx4* ov = reinterpret_cast<floatx4*>(out) + p * 2;
    __builtin_nontemporal_store(v0, ov);
    __builtin_nontemporal_store(v1, ov + 1);
}

// ---------------------------------------------------------------------------
extern "C" void kernel_launch(void* const* d_in, const int* in_sizes, int n_in,
                              void* d_out, int out_size, void* d_ws, size_t ws_size,
                              hipStream_t stream) {
    const float* x     = (const float*)d_in[0];
    const float* gamma = (const float*)d_in[1];
    const float* w1    = (const float*)d_in[2];
    const float* b1    = (const float*)d_in[3];
    const float* w2    = (const float*)d_in[4];
    const float* b2    = (const float*)d_in[5];
    float* out = (float*)d_out;

    char* ws = (char*)d_ws;
    size_t off = 0;
    float* pool  = (float*)(ws + off); off += (size_t)B * N * C * 4;      // 8 MB
    float* gate  = (float*)(ws + off); off += (size_t)B * N * C * 4;      // 8 MB
    float* w1t4  = (float*)(ws + off); off += (size_t)C8 * C * 4;         // 128 KB
    float* w2t4  = (float*)(ws + off); off += (size_t)C8 * C * 4;         // 128 KB
    float* carry = (float*)(ws + off); off += (size_t)B * SEG * C * 4;    // 256 KB
    float* ph    = (float*)(ws + off); off += (size_t)2 * ROWS * C8 * 4;  // 2 MB

    // chunk pooling: x -> pool [B,N,C] (also warms L3 with x)
    pool_k<<<B * 32 * 32, 256, 0, stream>>>(x, pool);
    // EMA segment carries (+ weight repack)
    emaA_k<<<(B * SEG * C) / 256, 256, 0, stream>>>(gamma, pool, carry, w1, w2, w1t4, w2t4);
    // SE GEMM1 with fused EMA finish (k-split 2)
    se1_k<<<128 * 2, 256, 0, stream>>>(pool, carry, gamma, w1t4, ph);
    // SE GEMM2 -> gate [B,C,N]
    se2_k<<<128 * 4, 256, 0, stream>>>(ph, b1, w2t4, b2, gate);
    // apply gate (NT stores keep x resident in L3)
    apply_k<<<(B * C * L / 8) / 256, 256, 0, stream>>>(x, gate, out);
}

// Round 7
// 95.258 us; speedup vs baseline: 1.1767x; 1.1767x over previous
//
#include <hip/hip_runtime.h>
#include <math.h>

#define B 8
#define C 512
#define L 8192
#define CS 16
#define N 512      // L/CS chunk steps
#define C8 64      // C/8 bottleneck dim
#define ROWS 4096  // B*N total chunk rows
#define CTILE 8    // channels per pool_ema block

// ---------------------------------------------------------------------------
// Kernel 1: fused pooling + full causal EMA.  x [B,C,L] -> e [B,N,C]
// Block = (b, 8-channel tile); owns the whole N timeline for its channels.
// Phase A: chunk means -> LDS (8-deep unrolled coalesced float4 reads).
// Phase B: segmented EMA scan in LDS (32 seg x 16 steps + serial carry fix).
// Also folds in the tiny weight re-pack (first 128 blocks).
// ---------------------------------------------------------------------------
__global__ __launch_bounds__(256) void pool_ema_k(
    const float* __restrict__ x, const float* __restrict__ gamma,
    float* __restrict__ e,
    const float* __restrict__ w1, const float* __restrict__ w2,
    float* __restrict__ w1t4, float* __restrict__ w2t4) {
    // per-channel stride 545 dwords: addr = cl*545 + s*17 + i  (s=seg, i=step)
    // 545%32==1, 17 coprime 32 -> scan axis conflict-free, channel axis spread
    __shared__ float cm[CTILE * 545];
    __shared__ float carry_s[CTILE][32];
    __shared__ float pre_s[CTILE][32];
    const int t = threadIdx.x;
    const int bid = blockIdx.x;          // B * 64 = 512
    const int ct = bid & 63;
    const int b = bid >> 6;

    // weight repack (first 128 blocks' threads)
    const int gid = bid * 256 + t;
    if (gid < C8 * C) {
        const int o = gid >> 9, k = gid & (C - 1);
        w1t4[((k >> 2) * C8 + o) * 4 + (k & 3)] = w1[gid];
        const int c2 = gid >> 6, k2 = gid & (C8 - 1);
        w2t4[((k2 >> 2) * C + c2) * 4 + (k2 & 3)] = w2[gid];
    }

    const int w = t >> 6, lane = t & 63;
    // ---- Phase A: chunk means. wave w covers channels w and w+4. ----
#pragma unroll
    for (int cr = 0; cr < 2; ++cr) {
        const int cl = w + 4 * cr;
        const size_t row4 = (size_t)(b * C + ct * CTILE + cl) * (L / 4);
#pragma unroll
        for (int r = 0; r < 4; ++r) {
            float4 f[8];
#pragma unroll
            for (int u = 0; u < 8; ++u)
                f[u] = reinterpret_cast<const float4*>(x)[row4 + r * 512 + u * 64 + lane];
#pragma unroll
            for (int u = 0; u < 8; ++u) {
                float s = f[u].x + f[u].y + f[u].z + f[u].w;
                s += __shfl_down(s, 1, 4);
                s += __shfl_down(s, 2, 4);
                if ((lane & 3) == 0) {
                    const int chunk = r * 128 + u * 16 + (lane >> 2);
                    cm[cl * 545 + (chunk >> 4) * 17 + (chunk & 15)] = s * (1.0f / 16.0f);
                }
            }
        }
    }
    __syncthreads();

    // ---- Phase B: EMA. thread = (cl = t>>5, s = t&31), 16 steps each. ----
    const int cl = t >> 5, s = t & 31;
    const float g = gamma[ct * CTILE + cl];
    const float omg = 1.0f - g;
    {
        float y = 0.0f;
#pragma unroll
        for (int i = 0; i < 16; ++i)
            y = fmaf(g, y, omg * cm[cl * 545 + s * 17 + i]);
        carry_s[cl][s] = y;
    }
    __syncthreads();
    if (t < CTILE) {
        const float gg = gamma[ct * CTILE + t];
        float g16 = gg * gg; g16 *= g16; g16 *= g16; g16 *= g16;   // g^16
        float E = 0.0f;
#pragma unroll
        for (int ss = 0; ss < 32; ++ss) {
            pre_s[t][ss] = E;                       // state entering segment ss
            E = fmaf(g16, E, carry_s[t][ss]);
        }
    }
    __syncthreads();
    {
        float y = pre_s[cl][s];
#pragma unroll
        for (int i = 0; i < 16; ++i) {
            y = fmaf(g, y, omg * cm[cl * 545 + s * 17 + i]);
            cm[cl * 545 + s * 17 + i] = y;
        }
    }
    __syncthreads();

    // ---- write e [B,N,C] ----
    float* ebase = e + (size_t)b * N * C + ct * CTILE;
#pragma unroll
    for (int r = 0; r < 16; ++r) {
        const int idx = r * 256 + t;              // 4096 values
        const int n = idx >> 3, c2 = idx & 7;
        ebase[(size_t)n * C + c2] = cm[c2 * 545 + (n >> 4) * 17 + (n & 15)];
    }
}

// ---------------------------------------------------------------------------
// Kernel 2: SE GEMM1.  e [ROWS][C] x w1t4 -> ph[ks][ROWS][C8]
// Grid: 128 row-blocks x 2 k-halves; register tile 2 o-cols x 4 rows.
// ---------------------------------------------------------------------------
__global__ __launch_bounds__(256) void se1_k(const float* __restrict__ e,
                                             const float* __restrict__ w1t4,
                                             float* __restrict__ ph) {
    __shared__ float e_s[32 * 256];   // 32KB: [row_local][k_half]
    const int t = threadIdx.x;
    const int rb = blockIdx.x >> 1;
    const int ks = blockIdx.x & 1;
    const int row0 = rb * 32;

    // stage 32 rows x 256 k (2048 float4, 8/thread), coalesced
#pragma unroll
    for (int i = 0; i < 8; ++i) {
        const int idx = i * 256 + t;        // 0..2047
        const int r = idx >> 6;             // 64 float4 per row-half
        const int kk = idx & 63;
        reinterpret_cast<float4*>(e_s)[idx] =
            reinterpret_cast<const float4*>(e + (size_t)(row0 + r) * C + ks * 256)[kk];
    }
    __syncthreads();

    const int oc = t & 31;
    const int jg = t >> 5;                  // rows jg*4..+3
    float a0[4] = {0.f, 0.f, 0.f, 0.f};
    float a1[4] = {0.f, 0.f, 0.f, 0.f};
    const float4* w1v = reinterpret_cast<const float4*>(w1t4);
    const float4* es4 = reinterpret_cast<const float4*>(e_s);
#pragma unroll 4
    for (int k4 = 0; k4 < 64; ++k4) {
        const float4 wa = w1v[(size_t)(ks * 64 + k4) * C8 + oc];
        const float4 wb = w1v[(size_t)(ks * 64 + k4) * C8 + oc + 32];
#pragma unroll
        for (int r = 0; r < 4; ++r) {
            const float4 ev = es4[(jg * 4 + r) * 64 + k4];
            a0[r] = fmaf(wa.x, ev.x, a0[r]); a0[r] = fmaf(wa.y, ev.y, a0[r]);
            a0[r] = fmaf(wa.z, ev.z, a0[r]); a0[r] = fmaf(wa.w, ev.w, a0[r]);
            a1[r] = fmaf(wb.x, ev.x, a1[r]); a1[r] = fmaf(wb.y, ev.y, a1[r]);
            a1[r] = fmaf(wb.z, ev.z, a1[r]); a1[r] = fmaf(wb.w, ev.w, a1[r]);
        }
    }
    float* pbase = ph + ((size_t)ks * ROWS + row0) * C8;
#pragma unroll
    for (int r = 0; r < 4; ++r) {
        pbase[(size_t)(jg * 4 + r) * C8 + oc]      = a0[r];
        pbase[(size_t)(jg * 4 + r) * C8 + oc + 32] = a1[r];
    }
}

// ---------------------------------------------------------------------------
// Kernel 3: SE GEMM2.  h = relu(b1 + ph0 + ph1); gate = sigmoid(h w2^T + b2)
// Output layout [B,C,N]: two float4 register stores per thread column.
// ---------------------------------------------------------------------------
__global__ __launch_bounds__(256) void se2_k(const float* __restrict__ ph,
                                             const float* __restrict__ b1,
                                             const float* __restrict__ w2t4,
                                             const float* __restrict__ b2,
                                             float* __restrict__ gate) {
    __shared__ float h_s[32 * C8];   // 8KB [row_local][o]
    const int t = threadIdx.x;
    const int rb = blockIdx.x >> 2;
    const int ct = blockIdx.x & 3;
    const int row0 = rb * 32;
    const int b = rb >> 4;
    const int n0 = (rb & 15) * 32;

    // stage h = relu(b1 + ph0 + ph1): 512 float4, 2/thread
    {
        const float4* p0 = reinterpret_cast<const float4*>(ph + (size_t)row0 * C8);
        const float4* p1 = reinterpret_cast<const float4*>(ph + (size_t)(ROWS + row0) * C8);
        const float4* b1v = reinterpret_cast<const float4*>(b1);
#pragma unroll
        for (int i = 0; i < 2; ++i) {
            const int idx = i * 256 + t;
            const float4 u = p0[idx];
            const float4 v = p1[idx];
            const float4 bb = b1v[idx & 15];
            float4 hv;
            hv.x = fmaxf(bb.x + u.x + v.x, 0.f);
            hv.y = fmaxf(bb.y + u.y + v.y, 0.f);
            hv.z = fmaxf(bb.z + u.z + v.z, 0.f);
            hv.w = fmaxf(bb.w + u.w + v.w, 0.f);
            reinterpret_cast<float4*>(h_s)[idx] = hv;
        }
    }
    __syncthreads();

    const int cl = t & 63;
    const int jg = t >> 6;                  // rows (n) jg*8..+7
    const int c = ct * 128 + cl;
    float acc0[8], acc1[8];
    const float bb0 = b2[c];
    const float bb1 = b2[c + 64];
#pragma unroll
    for (int j = 0; j < 8; ++j) { acc0[j] = bb0; acc1[j] = bb1; }
    const float4* w2v = reinterpret_cast<const float4*>(w2t4);
    const float4* hs4 = reinterpret_cast<const float4*>(h_s);
#pragma unroll
    for (int k4 = 0; k4 < 16; ++k4) {
        const float4 wa = w2v[(size_t)k4 * C + c];
        const float4 wb = w2v[(size_t)k4 * C + c + 64];
#pragma unroll
        for (int j = 0; j < 8; ++j) {
            const float4 hv = hs4[(jg * 8 + j) * 16 + k4];
            acc0[j] = fmaf(wa.x, hv.x, acc0[j]); acc0[j] = fmaf(wa.y, hv.y, acc0[j]);
            acc0[j] = fmaf(wa.z, hv.z, acc0[j]); acc0[j] = fmaf(wa.w, hv.w, acc0[j]);
            acc1[j] = fmaf(wb.x, hv.x, acc1[j]); acc1[j] = fmaf(wb.y, hv.y, acc1[j]);
            acc1[j] = fmaf(wb.z, hv.z, acc1[j]); acc1[j] = fmaf(wb.w, hv.w, acc1[j]);
        }
    }
    // gate [B,C,N]: 8 consecutive n per column per thread
    {
        float4 o0, o1;
        float* g0 = gate + ((size_t)(b * C + c)) * N + n0 + jg * 8;
        float* g1 = gate + ((size_t)(b * C + c + 64)) * N + n0 + jg * 8;
        o0.x = 1.0f / (1.0f + __expf(-acc0[0]));
        o0.y = 1.0f / (1.0f + __expf(-acc0[1]));
        o0.z = 1.0f / (1.0f + __expf(-acc0[2]));
        o0.w = 1.0f / (1.0f + __expf(-acc0[3]));
        o1.x = 1.0f / (1.0f + __expf(-acc0[4]));
        o1.y = 1.0f / (1.0f + __expf(-acc0[5]));
        o1.z = 1.0f / (1.0f + __expf(-acc0[6]));
        o1.w = 1.0f / (1.0f + __expf(-acc0[7]));
        reinterpret_cast<float4*>(g0)[0] = o0;
        reinterpret_cast<float4*>(g0)[1] = o1;
        o0.x = 1.0f / (1.0f + __expf(-acc1[0]));
        o0.y = 1.0f / (1.0f + __expf(-acc1[1]));
        o0.z = 1.0f / (1.0f + __expf(-acc1[2]));
        o0.w = 1.0f / (1.0f + __expf(-acc1[3]));
        o1.x = 1.0f / (1.0f + __expf(-acc1[4]));
        o1.y = 1.0f / (1.0f + __expf(-acc1[5]));
        o1.z = 1.0f / (1.0f + __expf(-acc1[6]));
        o1.w = 1.0f / (1.0f + __expf(-acc1[7]));
        reinterpret_cast<float4*>(g1)[0] = o0;
        reinterpret_cast<float4*>(g1)[1] = o1;
    }
}

// ---------------------------------------------------------------------------
// Kernel 4: apply gate.  out[b,c,l] = gate[b,c,l/16] * x[b,c,l]
// Plain float4 stores (NT regressed: memory-side L3 bypass lowers write BW).
// ---------------------------------------------------------------------------
__global__ __launch_bounds__(256) void apply_k(const float* __restrict__ x,
                                               const float* __restrict__ gate,
                                               float* __restrict__ out) {
    const size_t id = (size_t)blockIdx.x * 256 + threadIdx.x;   // float4 index
    const int per_row = L / 4;                   // 2048 float4 per (b,c) row
    const int bc = (int)(id / per_row);
    const int wi = (int)(id % per_row);
    const int n = wi >> 2;

    const float g = gate[(size_t)bc * N + n];
    float4 v = reinterpret_cast<const float4*>(x)[id];
    v.x *= g; v.y *= g; v.z *= g; v.w *= g;
    reinterpret_cast<float4*>(out)[id] = v;
}

// ---------------------------------------------------------------------------
extern "C" void kernel_launch(void* const* d_in, const int* in_sizes, int n_in,
                              void* d_out, int out_size, void* d_ws, size_t ws_size,
                              hipStream_t stream) {
    const float* x     = (const float*)d_in[0];
    const float* gamma = (const float*)d_in[1];
    const float* w1    = (const float*)d_in[2];
    const float* b1    = (const float*)d_in[3];
    const float* w2    = (const float*)d_in[4];
    const float* b2    = (const float*)d_in[5];
    float* out = (float*)d_out;

    char* ws = (char*)d_ws;
    size_t off = 0;
    float* e     = (float*)(ws + off); off += (size_t)B * N * C * 4;      // 8 MB
    float* gate  = (float*)(ws + off); off += (size_t)B * N * C * 4;      // 8 MB
    float* w1t4  = (float*)(ws + off); off += (size_t)C8 * C * 4;         // 128 KB
    float* w2t4  = (float*)(ws + off); off += (size_t)C8 * C * 4;         // 128 KB
    float* ph    = (float*)(ws + off); off += (size_t)2 * ROWS * C8 * 4;  // 2 MB

    // fused pooling + full EMA -> e [B,N,C]  (+ weight repack)
    pool_ema_k<<<B * 64, 256, 0, stream>>>(x, gamma, e, w1, w2, w1t4, w2t4);
    // SE GEMM1 (k-split 2)
    se1_k<<<128 * 2, 256, 0, stream>>>(e, w1t4, ph);
    // SE GEMM2 -> gate [B,C,N]
    se2_k<<<128 * 4, 256, 0, stream>>>(ph, b1, w2t4, b2, gate);
    // apply gate
    apply_k<<<(B * C * L / 4) / 256, 256, 0, stream>>>(x, gate, out);
}